// Round 10
// baseline (81.563 us; speedup 1.0000x reference)
//
#include <hip/hip_runtime.h>

// out[bg,d,h,w] = sum_c ref[bg,c,h,w]*tgt[bg,c,h,w-d]; B*G=16, Cg=64, H=128, W=256, D=48.
// Band-GEMM via bf16 MFMA, single k=64 chunk, one RTT exposure, 3 barriers.
#define HH 128
#define WW 256
#define CGR 64
#define ND 48
#define TPB 512            // 8 waves; wave wv owns n-tile nt=wv (w 16wv..16wv+15)
#define PITCH 72           // shorts per LDS row: 64 data + 8 pad (144 B, multiple of 16)
#define OPITCH 132         // f32 out-buffer pitch

typedef __attribute__((ext_vector_type(8))) short short8v;   // 8 bf16 = 4 VGPR
typedef __attribute__((ext_vector_type(4))) float float4v;   // MFMA C/D

__device__ __forceinline__ short f2bf(float x) {             // RNE f32->bf16
    unsigned u = __builtin_bit_cast(unsigned, x);
    u += 0x7fffu + ((u >> 16) & 1u);
    return (short)(u >> 16);
}

// rows 0..127 = ref w-row (w = W0+row); rows 128..303 = tgt w'-row (w' = W0-176+row).
// outb overlays the staging array (never live simultaneously).
union SMem {
    short st[304][PITCH];         // 43776 B bf16 [w-row][c]
    float outb[ND][OPITCH];       // 25344 B
};

__global__ __launch_bounds__(TPB, 4)
void gwc_mfma(const float* __restrict__ ref, const float* __restrict__ tgt,
              float* __restrict__ out) {
    __shared__ __align__(16) SMem sm;

    const int tid  = threadIdx.x;
    const int lane = tid & 63;
    const int wv   = tid >> 6;          // 0..7 = n-tile
    const int fr   = lane & 15;
    const int fhi  = lane >> 4;

    // XCD-chunked swizzle (grid 4096 = 8*512, bijective): dispatch i -> logical blk.
    const int blk  = ((blockIdx.x & 7) << 9) | (blockIdx.x >> 3);
    const int half = blk & 1;
    const int h    = (blk >> 1) & (HH - 1);
    const int bg   = blk >> 8;
    const int W0   = half << 7;

    const size_t cstride = (size_t)HH * WW;
    const float* refbase = ref + ((size_t)bg * CGR * HH + h) * WW;
    const float* tgtbase = tgt + ((size_t)bg * CGR * HH + h) * WW;

    // ---- staging: 1216 jobs = (row 0..303, c-quarter 0..3) over padded space 4*320.
    // job j: q = j/320, rowp = j%320 (valid if rowp<304). All q-boundaries (320,640,960)
    // are wave boundaries -> each wave-access is one 256B coalesced segment.
    float v0[16], v1[16], v2[16];
    int q0, r0, q1, r1, q2, r2; bool ok0, ok1, ok2;
    {
        const int j0 = tid;        q0 = j0 / 320; r0 = j0 % 320; ok0 = r0 < 304;
        const int j1 = tid + 512;  q1 = j1 / 320; r1 = j1 % 320; ok1 = r1 < 304;
        const int j2 = tid + 1024; q2 = j2 / 320; r2 = j2 % 320; ok2 = (tid < 256) && (r2 < 304);
    }
#define ISSUE(V, OK, Q, R)                                                        \
    if (OK) {                                                                     \
        const int wg = (R < 128) ? (W0 + R) : (W0 - 176 + R);                     \
        const float* p = ((R < 128) ? refbase : tgtbase) +                        \
                         (size_t)(Q * 16) * cstride + wg;                         \
        const bool ld = wg >= 0;                                                  \
        _Pragma("unroll")                                                         \
        for (int cc = 0; cc < 16; ++cc) V[cc] = ld ? p[(size_t)cc * cstride] : 0.0f; \
    }
    ISSUE(v0, ok0, q0, r0)
    ISSUE(v1, ok1, q1, r1)
    ISSUE(v2, ok2, q2, r2)
#undef ISSUE

#define CONVERT(V, OK, Q, R)                                                      \
    if (OK) {                                                                     \
        short* dst = &sm.st[R][16 * Q];                                           \
        _Pragma("unroll")                                                         \
        for (int g = 0; g < 4; ++g)                                               \
            *(short4*)(dst + 4 * g) = make_short4(f2bf(V[4*g]), f2bf(V[4*g+1]),   \
                                                  f2bf(V[4*g+2]), f2bf(V[4*g+3]));\
    }
    CONVERT(v0, ok0, q0, r0)
    CONVERT(v1, ok1, q1, r1)
    CONVERT(v2, ok2, q2, r2)
#undef CONVERT

    __syncthreads();

    // ---- band MFMAs: D[m=w'][n=w]; B = ref rows [16nt+fr], A = tgt rows [128+16mt+fr].
    // k = 32s + 8fhi + j (two k=32 slices of the 64-channel contraction).
    float4v acc[4];
    #pragma unroll
    for (int i = 0; i < 4; ++i) acc[i] = (float4v){0.f, 0.f, 0.f, 0.f};

    const short* brow = &sm.st[16 * wv + fr][8 * fhi];
    const short8v bfr0 = *(const short8v*)brow;            // s=0: k 0..31 slice
    const short8v bfr1 = *(const short8v*)(brow + 32);     // s=1: k 32..63 slice
    #pragma unroll
    for (int i = 0; i < 4; ++i) {
        const int mt = wv + i;                             // band tiles, mt <= 10
        const short* arow = &sm.st[128 + 16 * mt + fr][8 * fhi];
        acc[i] = __builtin_amdgcn_mfma_f32_16x16x32_bf16(
                     *(const short8v*)arow, bfr0, acc[i], 0, 0, 0);
        acc[i] = __builtin_amdgcn_mfma_f32_16x16x32_bf16(
                     *(const short8v*)(arow + 32), bfr1, acc[i], 0, 0, 0);
    }

    __syncthreads();   // WAR: outb overlays st

    // ---- scatter: d = w - w' = 48 - 16i + fr - 4fhi - rg (each (d,wl) exactly once)
    const int wl = 16 * wv + fr;
    #pragma unroll
    for (int i = 0; i < 4; ++i)
        #pragma unroll
        for (int rg = 0; rg < 4; ++rg) {
            const int d = 48 - 16 * i + fr - 4 * fhi - rg;
            if ((unsigned)d < (unsigned)ND) sm.outb[d][wl] = acc[i][rg];
        }
    __syncthreads();

    // ---- coalesced store: 1536 float4 jobs / 512 threads = 3 each ----
    #pragma unroll
    for (int k = 0; k < 3; ++k) {
        const int idx = tid + 512 * k;          // < 1536
        const int dd  = idx >> 5;
        const int wq  = idx & 31;
        const float4 vv = *(const float4*)&sm.outb[dd][4 * wq];
        *(float4*)(out + ((size_t)(bg * ND + dd) * HH + h) * WW + W0 + 4 * wq) = vv;
    }
}

extern "C" void kernel_launch(void* const* d_in, const int* in_sizes, int n_in,
                              void* d_out, int out_size, void* d_ws, size_t ws_size,
                              hipStream_t stream) {
    const float* ref = (const float*)d_in[0];
    const float* tgt = (const float*)d_in[1];
    float* out = (float*)d_out;
    gwc_mfma<<<dim3(16 * HH * 2), dim3(TPB), 0, stream>>>(ref, tgt, out);
}

// Round 11
// 79.982 us; speedup vs baseline: 1.0198x; 1.0198x over previous
//
#include <hip/hip_runtime.h>

// out[bg,d,h,w] = sum_c ref[bg,c,h,w]*tgt[bg,c,h,w-d]; B*G=16, Cg=64, H=128, W=256, D=48.
// Band-GEMM via bf16 MFMA. Staging: 19 wide float4 loads/thread (pinned in flight),
// transpose via b16 LDS scatter at bank-coprime pitch (33 dwords).
#define HH 128
#define WW 256
#define ND 48
#define TPB 256
#define PITCH 66           // shorts per st row (132 B = 33 dwords, coprime with 32 banks)
#define OPITCH 132         // f32 out-buffer pitch (33 dwords)

typedef __attribute__((ext_vector_type(8))) short short8v;   // 8 bf16
typedef __attribute__((ext_vector_type(4))) float float4v;   // MFMA C/D

__device__ __forceinline__ short f2bf(float x) {             // RNE f32->bf16
    unsigned u = __builtin_bit_cast(unsigned, x);
    u += 0x7fffu + ((u >> 16) & 1u);
    return (short)(u >> 16);
}

// frag rows are only 4B-aligned (pitch 132B): compose from 4 dword reads.
__device__ __forceinline__ short8v ld_frag(const short* p) {
    union { int i[4]; short8v v; } u;
    const int* q = (const int*)p;
    u.i[0] = q[0]; u.i[1] = q[1]; u.i[2] = q[2]; u.i[3] = q[3];
    return u.v;
}

// st rows 0..127: ref (w = W0+row); rows 128..303: tgt (w' = W0-176+row).
// outb overlays st (never live simultaneously). 40128 B -> 4 blocks/CU.
union SMem {
    short st[304 * PITCH];
    float outb[ND][OPITCH];
};

__global__ __launch_bounds__(TPB, 4)
void gwc_mfma(const float* __restrict__ ref, const float* __restrict__ tgt,
              float* __restrict__ out) {
    __shared__ __align__(16) SMem sm;

    const int tid  = threadIdx.x;
    const int lane = tid & 63;
    const int wv   = tid >> 6;          // wave 0..3: n-tiles {wv, wv+4}
    const int fr   = lane & 15;
    const int fhi  = lane >> 4;

    // XCD-chunked swizzle (grid 4096 = 8*512, bijective).
    const int blk  = ((blockIdx.x & 7) << 9) | (blockIdx.x >> 3);
    const int half = blk & 1;
    const int h    = (blk >> 1) & (HH - 1);
    const int bg   = blk >> 8;
    const int W0   = half << 7;

    const size_t cstride = (size_t)HH * WW;
    const float* refbase = ref + ((size_t)bg * 64 * HH + h) * WW;
    const float* tgtbase = tgt + ((size_t)bg * 64 * HH + h) * WW;

    // ---------- staging: issue all 19 float4 loads, then convert ----------
    // ref jobs p=0..7:  c = (tid>>5)+8p, w-quad q = tid&31  (j = tid+256p < 2048)
    // tgt jobs u=0..10: jt = tid+256u, c = jt/44, q = jt%44, w' = W0-48+4q
    float4 f[19];
    {
        const float* rp = refbase + (size_t)(tid >> 5) * cstride + (W0 + 4 * (tid & 31));
        #pragma unroll
        for (int p = 0; p < 8; ++p)
            f[p] = *(const float4*)(rp + (size_t)(8 * p) * cstride);
        #pragma unroll
        for (int u = 0; u < 11; ++u) {
            const int jt = tid + 256 * u;
            const int cc = (int)((unsigned)jt / 44u);
            const int q  = jt - 44 * cc;
            const int wg = W0 - 48 + 4 * q;
            const float* tp = tgtbase + (size_t)cc * cstride + (wg >= 0 ? wg : 0);
            f[8 + u] = *(const float4*)tp;
        }
    }
    __builtin_amdgcn_sched_barrier(0);   // keep all 19 loads in flight before converts
    {
        short* wp0 = &sm.st[(4 * (tid & 31)) * PITCH + (tid >> 5)];
        #pragma unroll
        for (int p = 0; p < 8; ++p) {
            short* wp = wp0 + 8 * p;
            wp[0 * PITCH] = f2bf(f[p].x);
            wp[1 * PITCH] = f2bf(f[p].y);
            wp[2 * PITCH] = f2bf(f[p].z);
            wp[3 * PITCH] = f2bf(f[p].w);
        }
        #pragma unroll
        for (int u = 0; u < 11; ++u) {
            const int jt = tid + 256 * u;
            const int cc = (int)((unsigned)jt / 44u);
            const int q  = jt - 44 * cc;
            const float vs = (W0 != 0 || q >= 12) ? 1.0f : 0.0f;  // halo -> zeros
            short* wp = &sm.st[(128 + 4 * q) * PITCH + cc];
            wp[0 * PITCH] = f2bf(f[8 + u].x * vs);
            wp[1 * PITCH] = f2bf(f[8 + u].y * vs);
            wp[2 * PITCH] = f2bf(f[8 + u].z * vs);
            wp[3 * PITCH] = f2bf(f[8 + u].w * vs);
        }
    }
    __syncthreads();

    // ---------- band MFMAs: D[m=w'][n=w], k = c (8fhi+j+32s) ----------
    float4v acc[2][4];
    #pragma unroll
    for (int t = 0; t < 2; ++t)
        #pragma unroll
        for (int i = 0; i < 4; ++i) acc[t][i] = (float4v){0.f, 0.f, 0.f, 0.f};

    #pragma unroll
    for (int s = 0; s < 2; ++s) {
        const int ko = 8 * fhi + 32 * s;
        #pragma unroll
        for (int t = 0; t < 2; ++t) {
            const int nt = wv + 4 * t;
            const short8v bf = ld_frag(&sm.st[(16 * nt + fr) * PITCH + ko]);
            #pragma unroll
            for (int i = 0; i < 4; ++i) {
                const short8v af = ld_frag(&sm.st[(128 + 16 * (nt + i) + fr) * PITCH + ko]);
                acc[t][i] = __builtin_amdgcn_mfma_f32_16x16x32_bf16(af, bf, acc[t][i], 0, 0, 0);
            }
        }
    }

    __syncthreads();   // WAR: outb overlays st

    // ---------- scatter: d = 48 - 16i + fr - 4fhi - rg (each (d,w) exactly once) ----------
    #pragma unroll
    for (int t = 0; t < 2; ++t) {
        const int wl = 16 * (wv + 4 * t) + fr;
        #pragma unroll
        for (int i = 0; i < 4; ++i)
            #pragma unroll
            for (int rg = 0; rg < 4; ++rg) {
                const int d = 48 - 16 * i + fr - 4 * fhi - rg;
                if ((unsigned)d < (unsigned)ND) sm.outb[d][wl] = acc[t][i][rg];
            }
    }
    __syncthreads();

    // ---------- coalesced store ----------
    #pragma unroll
    for (int k = 0; k < 6; ++k) {
        const int idx = tid + 256 * k;          // < 1536
        const int dd  = idx >> 5;
        const int wq  = idx & 31;
        *(float4*)(out + ((size_t)(bg * ND + dd) * HH + h) * WW + W0 + 4 * wq) =
            *(const float4*)&sm.outb[dd][4 * wq];
    }
}

extern "C" void kernel_launch(void* const* d_in, const int* in_sizes, int n_in,
                              void* d_out, int out_size, void* d_ws, size_t ws_size,
                              hipStream_t stream) {
    const float* ref = (const float*)d_in[0];
    const float* tgt = (const float*)d_in[1];
    float* out = (float*)d_out;
    gwc_mfma<<<dim3(16 * HH * 2), dim3(TPB), 0, stream>>>(ref, tgt, out);
}